// Round 1
// baseline (615.683 us; speedup 1.0000x reference)
//
#include <hip/hip_runtime.h>

#define NTH    256
#define ROWS   16
#define PADROW 484   // 480 + 4 pad floats; 484*4=1936 bytes, 16B-aligned rows

__global__ __launch_bounds__(NTH) void irreps_linear_kernel(
    const float* __restrict__ x,
    const float* __restrict__ modal_attr,
    const float* __restrict__ W0,
    const float* __restrict__ W0m,
    const float* __restrict__ W1,
    const float* __restrict__ W2,
    const int*   __restrict__ batch,
    float*       __restrict__ out,
    int N)
{
    __shared__ float tile[ROWS * PADROW];
    const int tid  = threadIdx.x;
    const int row0 = blockIdx.x * ROWS;

    // ---- stage 16 rows x 480 floats (one contiguous 30 KB chunk) ----
    {
        const float4* __restrict__ src =
            reinterpret_cast<const float4*>(x) + (size_t)row0 * 120;
        #pragma unroll
        for (int k = 0; k < 8; ++k) {          // 8*256 = 2048 slots >= 1920
            int idx = tid + k * NTH;
            if (idx < ROWS * 120) {
                float4 v = src[idx];
                int r = idx / 120;
                int c = idx - r * 120;
                *reinterpret_cast<float4*>(&tile[r * PADROW + c * 4]) = v;
            }
        }
    }
    __syncthreads();

    const int r = tid >> 4;      // 0..15 : row within tile
    const int t = tid & 15;      // 0..15 : column-slice id
    const int n = row0 + r;
    if (n >= N) return;
    const float* __restrict__ xrow = &tile[r * PADROW];
    float* __restrict__ orow = out + (size_t)n * 480;

    // ================= Phase A: out0 (128 cols, 8 per thread) =================
    {
        const int o0 = t * 8;
        float acc[8] = {0.f,0.f,0.f,0.f,0.f,0.f,0.f,0.f};
        for (int i = 0; i < 128; i += 4) {
            float4 xv = *reinterpret_cast<const float4*>(&xrow[i]);
            const float xs[4] = {xv.x, xv.y, xv.z, xv.w};
            #pragma unroll
            for (int ii = 0; ii < 4; ++ii) {
                const float* wp = &W0[(i + ii) * 128 + o0];
                float4 wa = *reinterpret_cast<const float4*>(wp);
                float4 wb = *reinterpret_cast<const float4*>(wp + 4);
                float xsv = xs[ii];
                acc[0] = fmaf(xsv, wa.x, acc[0]);
                acc[1] = fmaf(xsv, wa.y, acc[1]);
                acc[2] = fmaf(xsv, wa.z, acc[2]);
                acc[3] = fmaf(xsv, wa.w, acc[3]);
                acc[4] = fmaf(xsv, wb.x, acc[4]);
                acc[5] = fmaf(xsv, wb.y, acc[5]);
                acc[6] = fmaf(xsv, wb.z, acc[6]);
                acc[7] = fmaf(xsv, wb.w, acc[7]);
            }
        }
        const int   g  = batch[n];
        const float m0 = modal_attr[g * 2 + 0];
        const float m1 = modal_attr[g * 2 + 1];
        const float inv0 = 0.08770580217506079f;  // 1/sqrt(130)
        #pragma unroll
        for (int j = 0; j < 8; ++j) {
            acc[j] = (acc[j] + m0 * W0m[o0 + j] + m1 * W0m[128 + o0 + j]) * inv0;
        }
        *reinterpret_cast<float4*>(&orow[o0])     = make_float4(acc[0], acc[1], acc[2], acc[3]);
        *reinterpret_cast<float4*>(&orow[o0 + 4]) = make_float4(acc[4], acc[5], acc[6], acc[7]);
    }

    // ========== Phase B: out1 (64x64 per m, m=3; 4 o's x 3 m per thread) ==========
    {
        const int o0 = t * 4;
        float acc[12];
        #pragma unroll
        for (int j = 0; j < 12; ++j) acc[j] = 0.f;
        for (int i = 0; i < 64; i += 4) {
            const float* xp = &xrow[128 + i * 3];      // 12 consecutive floats, 16B aligned
            float4 xa = *reinterpret_cast<const float4*>(xp);
            float4 xb = *reinterpret_cast<const float4*>(xp + 4);
            float4 xc = *reinterpret_cast<const float4*>(xp + 8);
            const float xs[12] = {xa.x, xa.y, xa.z, xa.w,
                                  xb.x, xb.y, xb.z, xb.w,
                                  xc.x, xc.y, xc.z, xc.w};
            #pragma unroll
            for (int ii = 0; ii < 4; ++ii) {
                float4 w = *reinterpret_cast<const float4*>(&W1[(i + ii) * 64 + o0]);
                #pragma unroll
                for (int m = 0; m < 3; ++m) {
                    float xv = xs[ii * 3 + m];
                    acc[0 * 3 + m] = fmaf(xv, w.x, acc[0 * 3 + m]);
                    acc[1 * 3 + m] = fmaf(xv, w.y, acc[1 * 3 + m]);
                    acc[2 * 3 + m] = fmaf(xv, w.z, acc[2 * 3 + m]);
                    acc[3 * 3 + m] = fmaf(xv, w.w, acc[3 * 3 + m]);
                }
            }
        }
        const float inv1 = 0.125f;                     // 1/sqrt(64)
        #pragma unroll
        for (int j = 0; j < 12; ++j) acc[j] *= inv1;
        float* op = &orow[128 + o0 * 3];               // 12 contiguous floats, 16B aligned
        *reinterpret_cast<float4*>(&op[0]) = make_float4(acc[0], acc[1], acc[2],  acc[3]);
        *reinterpret_cast<float4*>(&op[4]) = make_float4(acc[4], acc[5], acc[6],  acc[7]);
        *reinterpret_cast<float4*>(&op[8]) = make_float4(acc[8], acc[9], acc[10], acc[11]);
    }

    // ========== Phase C: out2 (32x32 per m, m=5; 2 o's x 5 m per thread) ==========
    {
        const int o0 = t * 2;
        float acc[10];
        #pragma unroll
        for (int j = 0; j < 10; ++j) acc[j] = 0.f;
        for (int i = 0; i < 32; i += 4) {
            const float* xp = &xrow[320 + i * 5];      // 20 consecutive floats, 16B aligned
            float4 xa = *reinterpret_cast<const float4*>(xp);
            float4 xb = *reinterpret_cast<const float4*>(xp + 4);
            float4 xc = *reinterpret_cast<const float4*>(xp + 8);
            float4 xd = *reinterpret_cast<const float4*>(xp + 12);
            float4 xe = *reinterpret_cast<const float4*>(xp + 16);
            const float xs[20] = {xa.x, xa.y, xa.z, xa.w,
                                  xb.x, xb.y, xb.z, xb.w,
                                  xc.x, xc.y, xc.z, xc.w,
                                  xd.x, xd.y, xd.z, xd.w,
                                  xe.x, xe.y, xe.z, xe.w};
            #pragma unroll
            for (int ii = 0; ii < 4; ++ii) {
                float2 w = *reinterpret_cast<const float2*>(&W2[(i + ii) * 32 + o0]);
                #pragma unroll
                for (int m = 0; m < 5; ++m) {
                    float xv = xs[ii * 5 + m];
                    acc[m]     = fmaf(xv, w.x, acc[m]);
                    acc[5 + m] = fmaf(xv, w.y, acc[5 + m]);
                }
            }
        }
        const float inv2 = 0.17677669529663687f;       // 1/sqrt(32)
        #pragma unroll
        for (int j = 0; j < 10; ++j) acc[j] *= inv2;
        float* op = &orow[320 + o0 * 5];               // 10 contiguous floats, 8B aligned
        #pragma unroll
        for (int j = 0; j < 10; j += 2)
            *reinterpret_cast<float2*>(&op[j]) = make_float2(acc[j], acc[j + 1]);
    }
}

extern "C" void kernel_launch(void* const* d_in, const int* in_sizes, int n_in,
                              void* d_out, int out_size, void* d_ws, size_t ws_size,
                              hipStream_t stream) {
    const float* x     = (const float*)d_in[0];
    const float* modal = (const float*)d_in[1];
    const float* W0    = (const float*)d_in[2];
    const float* W0m   = (const float*)d_in[3];
    const float* W1    = (const float*)d_in[4];
    const float* W2    = (const float*)d_in[5];
    const int*   batch = (const int*)d_in[6];
    float* out = (float*)d_out;

    const int N = in_sizes[6];                 // 200000
    const int grid = (N + ROWS - 1) / ROWS;    // 12500 blocks
    irreps_linear_kernel<<<grid, NTH, 0, stream>>>(x, modal, W0, W0m, W1, W2, batch, out, N);
}

// Round 2
// 451.263 us; speedup vs baseline: 1.3644x; 1.3644x over previous
//
#include <hip/hip_runtime.h>

#define NTH   256
#define BROWS 64
#define PADA  132   // 128+4 floats, rows stay 16B-aligned
#define PADB  196   // 192+4
#define PADC  164   // 160+4

__device__ __forceinline__ void fma8(float (&acc)[8], float xv,
                                     const float4 wa, const float4 wb) {
    acc[0] = fmaf(xv, wa.x, acc[0]);
    acc[1] = fmaf(xv, wa.y, acc[1]);
    acc[2] = fmaf(xv, wa.z, acc[2]);
    acc[3] = fmaf(xv, wa.w, acc[3]);
    acc[4] = fmaf(xv, wb.x, acc[4]);
    acc[5] = fmaf(xv, wb.y, acc[5]);
    acc[6] = fmaf(xv, wb.z, acc[6]);
    acc[7] = fmaf(xv, wb.w, acc[7]);
}

__device__ __forceinline__ void loadW0(float4 (&wa)[4], float4 (&wb)[4],
                                       const float* __restrict__ W0, int i, int o0) {
    #pragma unroll
    for (int ii = 0; ii < 4; ++ii) {
        const float* p = W0 + (i + ii) * 128 + o0;
        wa[ii] = *reinterpret_cast<const float4*>(p);
        wb[ii] = *reinterpret_cast<const float4*>(p + 4);
    }
}

__device__ __forceinline__ void fmaA(float (&acc)[4][8],
                                     const float4 (&wa)[4], const float4 (&wb)[4],
                                     const float* __restrict__ tile,
                                     const int (&roff)[4], int i) {
    #pragma unroll
    for (int j = 0; j < 4; ++j) {
        float4 xv = *reinterpret_cast<const float4*>(&tile[roff[j] + i]);
        const float xs[4] = {xv.x, xv.y, xv.z, xv.w};
        #pragma unroll
        for (int ii = 0; ii < 4; ++ii)
            fma8(acc[j], xs[ii], wa[ii], wb[ii]);
    }
}

__device__ __forceinline__ void loadW1(float4 (&w)[4],
                                       const float* __restrict__ W1, int i, int o0) {
    #pragma unroll
    for (int ii = 0; ii < 4; ++ii)
        w[ii] = *reinterpret_cast<const float4*>(W1 + (i + ii) * 64 + o0);
}

__device__ __forceinline__ void fmaB(float (&acc)[4][12], const float4 (&w)[4],
                                     const float* __restrict__ tile,
                                     const int (&roff)[4], int i) {
    #pragma unroll
    for (int j = 0; j < 4; ++j) {
        const float* xp = &tile[roff[j] + i * 3];
        float4 xa = *reinterpret_cast<const float4*>(xp);
        float4 xb = *reinterpret_cast<const float4*>(xp + 4);
        float4 xc = *reinterpret_cast<const float4*>(xp + 8);
        const float xs[12] = {xa.x, xa.y, xa.z, xa.w,
                              xb.x, xb.y, xb.z, xb.w,
                              xc.x, xc.y, xc.z, xc.w};
        #pragma unroll
        for (int ii = 0; ii < 4; ++ii) {
            #pragma unroll
            for (int m = 0; m < 3; ++m) {
                float xv = xs[ii * 3 + m];
                acc[j][0 + m] = fmaf(xv, w[ii].x, acc[j][0 + m]);
                acc[j][3 + m] = fmaf(xv, w[ii].y, acc[j][3 + m]);
                acc[j][6 + m] = fmaf(xv, w[ii].z, acc[j][6 + m]);
                acc[j][9 + m] = fmaf(xv, w[ii].w, acc[j][9 + m]);
            }
        }
    }
}

__device__ __forceinline__ void loadW2(float2 (&w)[4],
                                       const float* __restrict__ W2, int i, int o0) {
    #pragma unroll
    for (int ii = 0; ii < 4; ++ii)
        w[ii] = *reinterpret_cast<const float2*>(W2 + (i + ii) * 32 + o0);
}

__device__ __forceinline__ void fmaC(float (&acc)[4][10], const float2 (&w)[4],
                                     const float* __restrict__ tile,
                                     const int (&roff)[4], int i) {
    #pragma unroll
    for (int j = 0; j < 4; ++j) {
        const float* xp = &tile[roff[j] + i * 5];
        float4 xa = *reinterpret_cast<const float4*>(xp);
        float4 xb = *reinterpret_cast<const float4*>(xp + 4);
        float4 xc = *reinterpret_cast<const float4*>(xp + 8);
        float4 xd = *reinterpret_cast<const float4*>(xp + 12);
        float4 xe = *reinterpret_cast<const float4*>(xp + 16);
        const float xs[20] = {xa.x, xa.y, xa.z, xa.w,
                              xb.x, xb.y, xb.z, xb.w,
                              xc.x, xc.y, xc.z, xc.w,
                              xd.x, xd.y, xd.z, xd.w,
                              xe.x, xe.y, xe.z, xe.w};
        #pragma unroll
        for (int ii = 0; ii < 4; ++ii) {
            #pragma unroll
            for (int m = 0; m < 5; ++m) {
                float xv = xs[ii * 5 + m];
                acc[j][m]     = fmaf(xv, w[ii].x, acc[j][m]);
                acc[j][5 + m] = fmaf(xv, w[ii].y, acc[j][5 + m]);
            }
        }
    }
}

__global__ __launch_bounds__(NTH, 3) void irreps_linear_kernel(
    const float* __restrict__ x,
    const float* __restrict__ modal_attr,
    const float* __restrict__ W0,
    const float* __restrict__ W0m,
    const float* __restrict__ W1,
    const float* __restrict__ W2,
    const int*   __restrict__ batch,
    float*       __restrict__ out,
    int N)
{
    __shared__ float tile[BROWS * PADB];   // 50176 B, reused by all 3 phases

    const int tid  = threadIdx.x;
    const int row0 = blockIdx.x * BROWS;
    const int t    = tid & 15;             // column-slice id
    const int rb   = tid >> 4;             // 0..15; thread owns rows rb+16j, j=0..3

    // hoist batch/modal lookups (latency hidden under staging)
    float m0j[4], m1j[4];
    #pragma unroll
    for (int j = 0; j < 4; ++j) {
        int n  = row0 + rb + 16 * j;
        int nc = n < N ? n : N - 1;
        int g  = batch[nc];
        m0j[j] = modal_attr[g * 2 + 0];
        m1j[j] = modal_attr[g * 2 + 1];
    }

    const float4* __restrict__ x4 = reinterpret_cast<const float4*>(x);

    // ================= Phase A: out0 = (x0 @ W0 + modal @ W0m) * inv0 =========
    // stage x[:, 0:128) : 64 rows x 32 float4
    #pragma unroll
    for (int k = 0; k < 8; ++k) {
        int idx = tid + k * NTH;           // 0..2047
        int rr  = idx >> 5;
        int cc  = idx & 31;
        int n   = row0 + rr;
        if (n < N) {
            float4 v = x4[(size_t)n * 120 + cc];
            *reinterpret_cast<float4*>(&tile[rr * PADA + cc * 4]) = v;
        }
    }
    __syncthreads();

    {
        const int o0 = t * 8;
        int roff[4];
        #pragma unroll
        for (int j = 0; j < 4; ++j) roff[j] = (rb + 16 * j) * PADA;

        float acc[4][8];
        #pragma unroll
        for (int j = 0; j < 4; ++j)
            #pragma unroll
            for (int c = 0; c < 8; ++c) acc[j][c] = 0.f;

        float4 wa0[4], wb0[4], wa1[4], wb1[4];
        loadW0(wa0, wb0, W0, 0, o0);
        for (int i = 0; i < 128; i += 8) {
            loadW0(wa1, wb1, W0, i + 4, o0);
            fmaA(acc, wa0, wb0, tile, roff, i);
            loadW0(wa0, wb0, W0, (i + 8) < 128 ? (i + 8) : 0, o0);
            fmaA(acc, wa1, wb1, tile, roff, i + 4);
        }

        float4 wm0a = *reinterpret_cast<const float4*>(&W0m[o0]);
        float4 wm0b = *reinterpret_cast<const float4*>(&W0m[o0 + 4]);
        float4 wm1a = *reinterpret_cast<const float4*>(&W0m[128 + o0]);
        float4 wm1b = *reinterpret_cast<const float4*>(&W0m[128 + o0 + 4]);
        const float wm0[8] = {wm0a.x, wm0a.y, wm0a.z, wm0a.w, wm0b.x, wm0b.y, wm0b.z, wm0b.w};
        const float wm1[8] = {wm1a.x, wm1a.y, wm1a.z, wm1a.w, wm1b.x, wm1b.y, wm1b.z, wm1b.w};
        const float inv0 = 0.08770580193070293f;  // 1/sqrt(130)

        #pragma unroll
        for (int j = 0; j < 4; ++j) {
            int n = row0 + rb + 16 * j;
            if (n < N) {
                float o[8];
                #pragma unroll
                for (int c = 0; c < 8; ++c)
                    o[c] = (acc[j][c] + m0j[j] * wm0[c] + m1j[j] * wm1[c]) * inv0;
                float* op = out + (size_t)n * 480 + o0;
                *reinterpret_cast<float4*>(op)     = make_float4(o[0], o[1], o[2], o[3]);
                *reinterpret_cast<float4*>(op + 4) = make_float4(o[4], o[5], o[6], o[7]);
            }
        }
    }
    __syncthreads();

    // ================= Phase B: out1, 64x64 per m (m=3) ========================
    // stage x[:, 128:320) : 64 rows x 48 float4
    #pragma unroll
    for (int k = 0; k < 12; ++k) {
        int idx = tid + k * NTH;           // 0..3071
        int rr  = idx / 48;
        int cc  = idx - rr * 48;
        int n   = row0 + rr;
        if (n < N) {
            float4 v = x4[(size_t)n * 120 + 32 + cc];
            *reinterpret_cast<float4*>(&tile[rr * PADB + cc * 4]) = v;
        }
    }
    __syncthreads();

    {
        const int o0 = t * 4;
        int roff[4];
        #pragma unroll
        for (int j = 0; j < 4; ++j) roff[j] = (rb + 16 * j) * PADB;

        float acc[4][12];
        #pragma unroll
        for (int j = 0; j < 4; ++j)
            #pragma unroll
            for (int c = 0; c < 12; ++c) acc[j][c] = 0.f;

        float4 w0[4], w1[4];
        loadW1(w0, W1, 0, o0);
        for (int i = 0; i < 64; i += 8) {
            loadW1(w1, W1, i + 4, o0);
            fmaB(acc, w0, tile, roff, i);
            loadW1(w0, W1, (i + 8) < 64 ? (i + 8) : 0, o0);
            fmaB(acc, w1, tile, roff, i + 4);
        }

        const float inv1 = 0.125f;         // 1/sqrt(64)
        #pragma unroll
        for (int j = 0; j < 4; ++j) {
            int n = row0 + rb + 16 * j;
            if (n < N) {
                float* op = out + (size_t)n * 480 + 128 + o0 * 3;
                *reinterpret_cast<float4*>(op)     = make_float4(acc[j][0] * inv1, acc[j][1] * inv1, acc[j][2]  * inv1, acc[j][3]  * inv1);
                *reinterpret_cast<float4*>(op + 4) = make_float4(acc[j][4] * inv1, acc[j][5] * inv1, acc[j][6]  * inv1, acc[j][7]  * inv1);
                *reinterpret_cast<float4*>(op + 8) = make_float4(acc[j][8] * inv1, acc[j][9] * inv1, acc[j][10] * inv1, acc[j][11] * inv1);
            }
        }
    }
    __syncthreads();

    // ================= Phase C: out2, 32x32 per m (m=5) ========================
    // stage x[:, 320:480) : 64 rows x 40 float4
    #pragma unroll
    for (int k = 0; k < 10; ++k) {
        int idx = tid + k * NTH;           // 0..2559
        int rr  = idx / 40;
        int cc  = idx - rr * 40;
        int n   = row0 + rr;
        if (n < N) {
            float4 v = x4[(size_t)n * 120 + 80 + cc];
            *reinterpret_cast<float4*>(&tile[rr * PADC + cc * 4]) = v;
        }
    }
    __syncthreads();

    {
        const int o0 = t * 2;
        int roff[4];
        #pragma unroll
        for (int j = 0; j < 4; ++j) roff[j] = (rb + 16 * j) * PADC;

        float acc[4][10];
        #pragma unroll
        for (int j = 0; j < 4; ++j)
            #pragma unroll
            for (int c = 0; c < 10; ++c) acc[j][c] = 0.f;

        float2 w0[4], w1[4];
        loadW2(w0, W2, 0, o0);
        for (int i = 0; i < 32; i += 8) {
            loadW2(w1, W2, i + 4, o0);
            fmaC(acc, w0, tile, roff, i);
            loadW2(w0, W2, (i + 8) < 32 ? (i + 8) : 0, o0);
            fmaC(acc, w1, tile, roff, i + 4);
        }

        const float inv2 = 0.17677669529663687f;  // 1/sqrt(32)
        #pragma unroll
        for (int j = 0; j < 4; ++j) {
            int n = row0 + rb + 16 * j;
            if (n < N) {
                float* op = out + (size_t)n * 480 + 320 + o0 * 5;
                #pragma unroll
                for (int c = 0; c < 10; c += 2)
                    *reinterpret_cast<float2*>(op + c) =
                        make_float2(acc[j][c] * inv2, acc[j][c + 1] * inv2);
            }
        }
    }
}

extern "C" void kernel_launch(void* const* d_in, const int* in_sizes, int n_in,
                              void* d_out, int out_size, void* d_ws, size_t ws_size,
                              hipStream_t stream) {
    const float* x     = (const float*)d_in[0];
    const float* modal = (const float*)d_in[1];
    const float* W0    = (const float*)d_in[2];
    const float* W0m   = (const float*)d_in[3];
    const float* W1    = (const float*)d_in[4];
    const float* W2    = (const float*)d_in[5];
    const int*   batch = (const int*)d_in[6];
    float* out = (float*)d_out;

    const int N    = in_sizes[6];                   // 200000
    const int grid = (N + BROWS - 1) / BROWS;       // 3125 blocks
    irreps_linear_kernel<<<grid, NTH, 0, stream>>>(x, modal, W0, W0m, W1, W2, batch, out, N);
}

// Round 3
// 183.633 us; speedup vs baseline: 3.3528x; 2.4574x over previous
//
#include <hip/hip_runtime.h>

// ---------------------------------------------------------------------------
// IrrepsLinear via bf16 hi/lo-split MFMA (gfx950).
//   out0 = (x0 @ W0 + modal @ W0m) / sqrt(130)      x0: [N,128], W0: 128x128
//   out1 = einsum('nim,io', x1, W1) / 8             x1: [N,64,3], W1: 64x64
//   out2 = einsum('nim,io', x2, W2) / sqrt(32)      x2: [N,32,5], W2: 32x32
// fp32 operands split: v = hi + lo (both bf16); v*w ~ vh*wh + vl*wh + vh*wl
// (error ~2^-16 rel). Weights pre-split into d_ws in MFMA B-frag layout.
// ---------------------------------------------------------------------------

typedef __attribute__((ext_vector_type(8))) short  short8;   // bf16x8 frag (4 VGPR)
typedef __attribute__((ext_vector_type(4))) float  f32x4;    // acc frag

#define NTH 256
#define BR  32

// ws layout in ushort units: [W0H 0][W0L 16384][W1H 32768][W1L 36864][W2H 40960][W2L 41984]
#define W0H 0
#define W0L 16384
#define W1H 32768
#define W1L 36864
#define W2H 40960
#define W2L 41984
// total 43008 ushorts = 86016 bytes of d_ws

__device__ __forceinline__ void split_bf16(float v, unsigned short& h, unsigned short& l) {
    unsigned u  = __float_as_uint(v);
    unsigned uh = u & 0xFFFF0000u;                 // truncate -> hi
    h = (unsigned short)(uh >> 16);
    float r = v - __uint_as_float(uh);             // exact residual in fp32
    unsigned ur = __float_as_uint(r);
    ur += 0x7FFFu + ((ur >> 16) & 1u);             // round-to-nearest-even -> lo
    l = (unsigned short)(ur >> 16);
}

// --------------------------- weight prep kernel ----------------------------
// Writes hi/lo bf16 weights in B-fragment order:
//   slot s = ((ct*NKT + kt)*64 + lane)*8 + j  holds  W[k][col],
//   col = ct*16 + (lane&15), k = kt*32 + (lane>>4)*8 + j.
__global__ void prep_weights(const float* __restrict__ W0,
                             const float* __restrict__ W1,
                             const float* __restrict__ W2,
                             unsigned short* __restrict__ ws) {
    const int s0     = blockIdx.x * blockDim.x + threadIdx.x;
    const int STRIDE = gridDim.x * blockDim.x;
    for (int s = s0; s < 16384; s += STRIDE) {     // W0: ct 0..7, kt 0..3
        int j = s & 7, l = (s >> 3) & 63, kt = (s >> 9) & 3, ct = s >> 11;
        int col = ct * 16 + (l & 15);
        int k   = kt * 32 + (l >> 4) * 8 + j;
        unsigned short h, lo;
        split_bf16(W0[k * 128 + col], h, lo);
        ws[W0H + s] = h; ws[W0L + s] = lo;
    }
    for (int s = s0; s < 4096; s += STRIDE) {      // W1: ct 0..3, kt 0..1
        int j = s & 7, l = (s >> 3) & 63, kt = (s >> 9) & 1, ct = s >> 10;
        int col = ct * 16 + (l & 15);
        int k   = kt * 32 + (l >> 4) * 8 + j;
        unsigned short h, lo;
        split_bf16(W1[k * 64 + col], h, lo);
        ws[W1H + s] = h; ws[W1L + s] = lo;
    }
    for (int s = s0; s < 1024; s += STRIDE) {      // W2: ct 0..1, kt = 0
        int j = s & 7, l = (s >> 3) & 63, ct = s >> 9;
        int col = ct * 16 + (l & 15);
        int k   = (l >> 4) * 8 + j;
        unsigned short h, lo;
        split_bf16(W2[k * 32 + col], h, lo);
        ws[W2H + s] = h; ws[W2L + s] = lo;
    }
}

// build hi/lo A-frags from 8 contiguous fp32 in LDS
__device__ __forceinline__ void frag_from_f32(const float* __restrict__ p,
                                              short8& hi, short8& lo) {
    f32x4 a = *reinterpret_cast<const f32x4*>(p);
    f32x4 b = *reinterpret_cast<const f32x4*>(p + 4);
    #pragma unroll
    for (int j = 0; j < 4; ++j) {
        unsigned short h, s;
        split_bf16(a[j], h, s); hi[j]     = (short)h; lo[j]     = (short)s;
        split_bf16(b[j], h, s); hi[4 + j] = (short)h; lo[4 + j] = (short)s;
    }
}

#define MFMA(a, b, c) __builtin_amdgcn_mfma_f32_16x16x32_bf16((a), (b), (c), 0, 0, 0)

// ------------------------------ main kernel --------------------------------
// 4 waves/block; wave w: rows rb0=(w>>1)*16 .. +16, col-half ch=w&1.
// Phase tiles in one shared buffer (max 3*32*68 floats = 26112 B).
__global__ __launch_bounds__(NTH, 4) void irreps_mfma_kernel(
    const float* __restrict__ x,
    const float* __restrict__ modal_attr,
    const float* __restrict__ W0m,
    const unsigned short* __restrict__ wsf,
    const int*   __restrict__ batch,
    float*       __restrict__ out,
    int N)
{
    __shared__ float lds[3 * BR * 68];   // 26112 bytes, reused by all phases

    const int tid  = threadIdx.x;
    const int w    = tid >> 6;           // wave id 0..3
    const int l    = tid & 63;           // lane
    const int r    = l & 15;             // frag row/col index
    const int kg   = l >> 4;             // k-group 0..3
    const int rb0  = (w >> 1) * 16;      // row-group base within tile
    const int ch   = w & 1;              // column half
    const int row0 = blockIdx.x * BR;
    const int arow = rb0 + r;            // A-frag row within tile

    // store rows for C/D layout: row = kg*4 + reg ; hoist modal lookups
    int nr[4]; float am0[4], am1[4];
    #pragma unroll
    for (int reg = 0; reg < 4; ++reg) {
        int n  = row0 + rb0 + kg * 4 + reg;
        nr[reg] = n;
        int nc = n < N ? n : N - 1;
        int g  = batch[nc];
        am0[reg] = modal_attr[2 * g];
        am1[reg] = modal_attr[2 * g + 1];
    }

    const float4* __restrict__ x4 = reinterpret_cast<const float4*>(x);

    // ======================= Phase A : out0 (K=128) ========================
    // stage x[:,0:128) -> lds rows of 132 floats (132 % 32 == 4 -> 2-way max)
    #pragma unroll
    for (int k = 0; k < 4; ++k) {
        int idx = tid + k * NTH;          // 0..1023
        int rr = idx >> 5, cc = idx & 31;
        int n  = row0 + rr;
        float4 v = x4[(size_t)(n < N ? n : N - 1) * 120 + cc];
        *reinterpret_cast<float4*>(&lds[rr * 132 + cc * 4]) = v;
    }
    __syncthreads();

    {
        short8 ah[4], al[4];
        #pragma unroll
        for (int kt = 0; kt < 4; ++kt)
            frag_from_f32(&lds[arow * 132 + kt * 32 + kg * 8], ah[kt], al[kt]);

        #pragma unroll
        for (int ci = 0; ci < 4; ++ci) {
            int ct = ch * 4 + ci;
            short8 bh[4], bl[4];
            #pragma unroll
            for (int kt = 0; kt < 4; ++kt) {
                int b = ct * 4 + kt;
                bh[kt] = *reinterpret_cast<const short8*>(wsf + W0H + (size_t)(b * 64 + l) * 8);
                bl[kt] = *reinterpret_cast<const short8*>(wsf + W0L + (size_t)(b * 64 + l) * 8);
            }
            f32x4 acc = {0.f, 0.f, 0.f, 0.f};
            #pragma unroll
            for (int kt = 0; kt < 4; ++kt) {
                acc = MFMA(ah[kt], bh[kt], acc);
                acc = MFMA(al[kt], bh[kt], acc);
                acc = MFMA(ah[kt], bl[kt], acc);
            }
            int col = ct * 16 + r;
            float wm0 = W0m[col], wm1 = W0m[128 + col];
            #pragma unroll
            for (int reg = 0; reg < 4; ++reg) {
                if (nr[reg] < N)
                    out[(size_t)nr[reg] * 480 + col] =
                        (acc[reg] + am0[reg] * wm0 + am1[reg] * wm1) * 0.08770580193070293f;
            }
        }
    }
    __syncthreads();

    // ======================= Phase B : out1 (m=3, K=64) ====================
    // stage x[:,128:320) de-interleaved: tile1[m][32][68]
    #pragma unroll
    for (int k = 0; k < 2; ++k) {
        int idx = tid + k * NTH;          // 0..511
        int rr = idx >> 4, ig = idx & 15; // row, i-group (4 i's)
        int n  = row0 + rr;
        const float4* src = &x4[(size_t)(n < N ? n : N - 1) * 120 + 32 + ig * 3];
        float4 f0 = src[0], f1 = src[1], f2 = src[2];
        *reinterpret_cast<float4*>(&lds[(0 * BR + rr) * 68 + ig * 4]) = make_float4(f0.x, f0.w, f1.z, f2.y);
        *reinterpret_cast<float4*>(&lds[(1 * BR + rr) * 68 + ig * 4]) = make_float4(f0.y, f1.x, f1.w, f2.z);
        *reinterpret_cast<float4*>(&lds[(2 * BR + rr) * 68 + ig * 4]) = make_float4(f0.z, f1.y, f2.x, f2.w);
    }
    __syncthreads();

    {
        short8 ah1[3][2], al1[3][2];
        #pragma unroll
        for (int m = 0; m < 3; ++m)
            #pragma unroll
            for (int kt = 0; kt < 2; ++kt)
                frag_from_f32(&lds[(m * BR + arow) * 68 + kt * 32 + kg * 8],
                              ah1[m][kt], al1[m][kt]);

        #pragma unroll
        for (int ci = 0; ci < 2; ++ci) {
            int ct = ch * 2 + ci;
            short8 bh[2], bl[2];
            #pragma unroll
            for (int kt = 0; kt < 2; ++kt) {
                int b = ct * 2 + kt;
                bh[kt] = *reinterpret_cast<const short8*>(wsf + W1H + (size_t)(b * 64 + l) * 8);
                bl[kt] = *reinterpret_cast<const short8*>(wsf + W1L + (size_t)(b * 64 + l) * 8);
            }
            f32x4 accm[3];
            #pragma unroll
            for (int m = 0; m < 3; ++m) {
                f32x4 acc = {0.f, 0.f, 0.f, 0.f};
                #pragma unroll
                for (int kt = 0; kt < 2; ++kt) {
                    acc = MFMA(ah1[m][kt], bh[kt], acc);
                    acc = MFMA(al1[m][kt], bh[kt], acc);
                    acc = MFMA(ah1[m][kt], bl[kt], acc);
                }
                accm[m] = acc;
            }
            int cb = 128 + 3 * (ct * 16 + r);
            #pragma unroll
            for (int reg = 0; reg < 4; ++reg) {
                if (nr[reg] < N) {
                    size_t base = (size_t)nr[reg] * 480 + cb;
                    out[base]     = accm[0][reg] * 0.125f;
                    out[base + 1] = accm[1][reg] * 0.125f;
                    out[base + 2] = accm[2][reg] * 0.125f;
                }
            }
        }
    }
    __syncthreads();

    // ======================= Phase C : out2 (m=5, K=32) ====================
    // stage x[:,320:480) de-interleaved: tile2[m][32][36]
    {
        int rr = tid >> 3, ig = tid & 7;  // 32 rows x 8 i-groups
        int n  = row0 + rr;
        const float4* src = &x4[(size_t)(n < N ? n : N - 1) * 120 + 80 + ig * 5];
        float f[20];
        #pragma unroll
        for (int q = 0; q < 5; ++q) {
            float4 v = src[q];
            f[q * 4 + 0] = v.x; f[q * 4 + 1] = v.y; f[q * 4 + 2] = v.z; f[q * 4 + 3] = v.w;
        }
        #pragma unroll
        for (int m = 0; m < 5; ++m)
            *reinterpret_cast<float4*>(&lds[(m * BR + rr) * 36 + ig * 4]) =
                make_float4(f[m], f[m + 5], f[m + 10], f[m + 15]);
    }
    __syncthreads();

    {
        short8 ah2[5], al2[5];
        #pragma unroll
        for (int m = 0; m < 5; ++m)
            frag_from_f32(&lds[(m * BR + arow) * 36 + kg * 8], ah2[m], al2[m]);

        int ct = ch;
        short8 bh = *reinterpret_cast<const short8*>(wsf + W2H + (size_t)(ct * 64 + l) * 8);
        short8 bl = *reinterpret_cast<const short8*>(wsf + W2L + (size_t)(ct * 64 + l) * 8);

        f32x4 accm[5];
        #pragma unroll
        for (int m = 0; m < 5; ++m) {
            f32x4 acc = {0.f, 0.f, 0.f, 0.f};
            acc = MFMA(ah2[m], bh, acc);
            acc = MFMA(al2[m], bh, acc);
            acc = MFMA(ah2[m], bl, acc);
            accm[m] = acc;
        }
        int cb = 320 + 5 * (ct * 16 + r);
        #pragma unroll
        for (int reg = 0; reg < 4; ++reg) {
            if (nr[reg] < N) {
                size_t base = (size_t)nr[reg] * 480 + cb;
                #pragma unroll
                for (int m = 0; m < 5; ++m)
                    out[base + m] = accm[m][reg] * 0.17677669529663687f;
            }
        }
    }
}

extern "C" void kernel_launch(void* const* d_in, const int* in_sizes, int n_in,
                              void* d_out, int out_size, void* d_ws, size_t ws_size,
                              hipStream_t stream) {
    const float* x     = (const float*)d_in[0];
    const float* modal = (const float*)d_in[1];
    const float* W0    = (const float*)d_in[2];
    const float* W0m   = (const float*)d_in[3];
    const float* W1    = (const float*)d_in[4];
    const float* W2    = (const float*)d_in[5];
    const int*   batch = (const int*)d_in[6];
    float* out = (float*)d_out;
    unsigned short* ws = (unsigned short*)d_ws;   // needs 86016 B

    const int N = in_sizes[6];                    // 200000

    prep_weights<<<84, NTH, 0, stream>>>(W0, W1, W2, ws);

    const int grid = (N + BR - 1) / BR;           // 6250 blocks
    irreps_mfma_kernel<<<grid, NTH, 0, stream>>>(x, modal, W0m, ws, batch, out, N);
}